// Round 8
// baseline (98.905 us; speedup 1.0000x reference)
//
#include <hip/hip_runtime.h>
#include <hip/hip_bf16.h>

typedef __bf16 bf16x8 __attribute__((ext_vector_type(8)));
typedef __bf16 bf16x4 __attribute__((ext_vector_type(4)));
typedef short  s16x4  __attribute__((ext_vector_type(4)));
typedef float  f32x16 __attribute__((ext_vector_type(16)));
typedef int    i32x2  __attribute__((ext_vector_type(2)));

constexpr int QN  = 128;   // query rows
constexpr int KN  = 2048;  // memory rows
constexpr int D5  = 768;
constexpr int SL  = 32;    // seq_len (t and s extent)
constexpr int ZD  = 24;    // per-token sub-dim
constexpr int KCH = 8;     // k's per chunk
constexpr int WPB = 8;     // waves per block
constexpr int NKC = 4;     // chunks per block (pipelined)

#if __has_builtin(__builtin_amdgcn_mfma_f32_32x32x8bf16_1k)
#define HAVE_MFMA_X8 1
#else
#define HAVE_MFMA_X8 0
#endif

#if __has_builtin(__builtin_amdgcn_permlane32_swap)
#define HAVE_PERMLANE32 1
#else
#define HAVE_PERMLANE32 0
#endif

static __device__ __forceinline__ float max3f(float a, float b, float c) {
    return fmaxf(fmaxf(a, b), c);   // fuses to v_max3_f32
}

static __device__ __forceinline__ float redmax16(const f32x16& a) {
    float x0 = max3f(a[0],  a[1],  a[2]);
    float x1 = max3f(a[3],  a[4],  a[5]);
    float x2 = max3f(a[6],  a[7],  a[8]);
    float x3 = max3f(a[9],  a[10], a[11]);
    float x4 = max3f(a[12], a[13], a[14]);
    float y0 = max3f(x0, x1, x2);
    float y1 = max3f(x3, x4, a[15]);
    return fmaxf(y0, y1);
}

// max with lane^32's value on the VALU (v_permlane32_swap), not LDS bpermute
static __device__ __forceinline__ float halfmax(float m) {
#if HAVE_PERMLANE32
    i32x2 pr = __builtin_amdgcn_permlane32_swap(__builtin_bit_cast(int, m),
                                                __builtin_bit_cast(int, m),
                                                false, false);
    return fmaxf(__builtin_bit_cast(float, pr[0]), __builtin_bit_cast(float, pr[1]));
#else
    return fmaxf(m, __shfl_xor(m, 32));
#endif
}

#if HAVE_MFMA_X8
static __device__ __forceinline__ short f2bfbits(float x) {
    __bf16 b = (__bf16)x;
    return __builtin_bit_cast(short, b);
}
#endif

// R8: R5's persistent pipelined structure + bijective XCD swizzle.
// R5's counters (FETCH 72.6MB, hbm 2.5TB/s) showed its 45.5us was MEMORY-
// paced: 1024 resident blocks round-robin onto 8 XCDs, so each XCD's 128
// blocks spanned ~all 64 kcg = 6MB of mem > 4MiB L2 -> thrash. The pipelined
// compute structure (staging hidden under pair loop, single generation, no
// inter-generation barrier convoys) was never actually tested. Fix: flatten
// the grid and remap swz=(bid&7)*128+(bid>>3): assuming round-robin bid->XCD,
// each XCD gets a contiguous 8-kcg band (8 x 96KB = 768KB of mem, L2-fit)
// x all 16 qg (tgt 393KB, L2-fit). Wrong mapping assumption costs only speed.
__global__ __launch_bounds__(512, 8) void matcher_kernel(const float* __restrict__ tgt,
                                                         const float* __restrict__ mem,
                                                         float* __restrict__ out)
{
    // Per chunk, per k: chunk0 = 64 lanes x 16B (d0-15), chunk1 = 32 rows x 16B
    // (d16-23) => 768 elements. Double-buffered: 2 x 12 KB.
    __shared__ __align__(16) __bf16 Kf[2][KCH * 768];
    // Per-wave epilogue buffer: [pair][32 swizzled maxes]. 1 KB/wave, 8 KB.
    __shared__ float vbuf[WPB][KCH * 32];

    const int tid = threadIdx.x;
    // ---- XCD-aware remap (assumes bid -> XCD bid%8 round-robin) ----
    const int bid = blockIdx.x;               // 0..1023
    const int swz = ((bid & 7) << 7) + (bid >> 3);
    const int kcg = swz >> 4;                 // 0..63 — contiguous 8-band per XCD
    const int qg  = swz & 15;                 // 0..15

    // ---- staging geometry (wave-uniform halves) ----
    const int sr  = tid & 255;    // row 0..255 = (kl, s)
    const int hf  = tid >> 8;     // 0: d0-11 (waves 0-3), 1: d12-23 (waves 4-7)
    const int skl = sr >> 5;
    const int ss  = sr & 31;

    float4 pf0, pf1, pf2;         // prefetch registers (12 VGPRs)

    // issue chunk-0 global loads
    {
        const int k0c = (kcg * NKC + 0) * KCH;
        const float* src = mem + (size_t)(k0c + skl) * D5 + ss * ZD + hf * 12;
        pf0 = ((const float4*)src)[0];
        pf1 = ((const float4*)src)[1];
        pf2 = ((const float4*)src)[2];
    }

    // ---- per-wave Q fragments (registers, live across all chunks) ----
    const int lane = tid & 63;
    const int wv   = tid >> 6;   // 0..7
    const int t    = lane & 31;
    const int h    = lane >> 5;
    const int q    = qg * WPB + wv;

    const float4* p4 = (const float4*)(tgt + (size_t)q * D5 + t * ZD);
    bf16x8 aQ0;
    {
        float4 u0 = p4[2 * h], u1 = p4[2 * h + 1];  // d = h*8 .. h*8+7
        aQ0[0] = (__bf16)u0.x; aQ0[1] = (__bf16)u0.y; aQ0[2] = (__bf16)u0.z; aQ0[3] = (__bf16)u0.w;
        aQ0[4] = (__bf16)u1.x; aQ0[5] = (__bf16)u1.y; aQ0[6] = (__bf16)u1.z; aQ0[7] = (__bf16)u1.w;
    }
#if HAVE_MFMA_X8
    s16x4 aQ1;   // 32x32x8 fragment: lane holds d = 16 + h*4 + j
    {
        float4 w = p4[4 + h];
        aQ1[0] = f2bfbits(w.x); aQ1[1] = f2bfbits(w.y);
        aQ1[2] = f2bfbits(w.z); aQ1[3] = f2bfbits(w.w);
    }
#else
    bf16x8 aQ1;
    if (h == 0) {
        float4 w0 = p4[4], w1 = p4[5];              // d = 16..23
        aQ1[0] = (__bf16)w0.x; aQ1[1] = (__bf16)w0.y; aQ1[2] = (__bf16)w0.z; aQ1[3] = (__bf16)w0.w;
        aQ1[4] = (__bf16)w1.x; aQ1[5] = (__bf16)w1.y; aQ1[6] = (__bf16)w1.z; aQ1[7] = (__bf16)w1.w;
    } else {
#pragma unroll
        for (int j = 0; j < 8; ++j) aQ1[j] = (__bf16)0.0f;
    }
#endif

    f32x16 zacc;
#pragma unroll
    for (int i = 0; i < 16; ++i) zacc[i] = 0.0f;

    // ---- write chunk 0 into buffer 0 ----
    {
        __bf16* base = Kf[0] + skl * 768;
        if (hf == 0) {   // wave-uniform branch
            bf16x8 a;
            a[0] = (__bf16)pf0.x; a[1] = (__bf16)pf0.y; a[2] = (__bf16)pf0.z; a[3] = (__bf16)pf0.w;
            a[4] = (__bf16)pf1.x; a[5] = (__bf16)pf1.y; a[6] = (__bf16)pf1.z; a[7] = (__bf16)pf1.w;
            *(bf16x8*)(base + ss * 8) = a;                       // d0-7
            bf16x4 b;
            b[0] = (__bf16)pf2.x; b[1] = (__bf16)pf2.y; b[2] = (__bf16)pf2.z; b[3] = (__bf16)pf2.w;
            *(bf16x4*)(base + (32 + ss) * 8) = b;                // d8-11
        } else {
            bf16x4 b;
            b[0] = (__bf16)pf0.x; b[1] = (__bf16)pf0.y; b[2] = (__bf16)pf0.z; b[3] = (__bf16)pf0.w;
            *(bf16x4*)(base + (32 + ss) * 8 + 4) = b;            // d12-15
            bf16x8 cdat;
            cdat[0] = (__bf16)pf1.x; cdat[1] = (__bf16)pf1.y; cdat[2] = (__bf16)pf1.z; cdat[3] = (__bf16)pf1.w;
            cdat[4] = (__bf16)pf2.x; cdat[5] = (__bf16)pf2.y; cdat[6] = (__bf16)pf2.z; cdat[7] = (__bf16)pf2.w;
            *(bf16x8*)(base + 512 + ss * 8) = cdat;              // d16-23
        }
    }
    __syncthreads();

    float* vb = vbuf[wv];

    // ---- chunk loop ----
    for (int c = 0; c < NKC; ++c) {
        const int buf = c & 1;
        const int k0  = (kcg * NKC + c) * KCH;

        // issue next chunk's global loads (latency hides under pair loop)
        if (c + 1 < NKC) {
            const int k0n = k0 + KCH;
            const float* src = mem + (size_t)(k0n + skl) * D5 + ss * ZD + hf * 12;
            pf0 = ((const float4*)src)[0];
            pf1 = ((const float4*)src)[1];
            pf2 = ((const float4*)src)[2];
        }

        // ---- pair loop: (q, k0+kl) for kl = 0..KCH-1 ----
#pragma unroll 4
        for (int kl = 0; kl < KCH; ++kl) {
            const __bf16* lb = Kf[buf] + kl * 768;
            bf16x8 bK0 = *(const bf16x8*)(lb + lane * 8);
#if HAVE_MFMA_X8
            s16x4 bK1 = *(const s16x4*)(lb + 512 + t * 8 + h * 4);

            f32x16 accS = __builtin_amdgcn_mfma_f32_32x32x16_bf16(aQ0, bK0, zacc, 0, 0, 0);
            accS = __builtin_amdgcn_mfma_f32_32x32x8bf16_1k(aQ1, bK1, accS, 0, 0, 0);
            f32x16 accT = __builtin_amdgcn_mfma_f32_32x32x16_bf16(bK0, aQ0, zacc, 0, 0, 0);
            accT = __builtin_amdgcn_mfma_f32_32x32x8bf16_1k(bK1, aQ1, accT, 0, 0, 0);
#else
            bf16x8 bK1 = *(const bf16x8*)(lb + 512 + t * 8);

            f32x16 accS = __builtin_amdgcn_mfma_f32_32x32x16_bf16(aQ0, bK0, zacc, 0, 0, 0);
            accS        = __builtin_amdgcn_mfma_f32_32x32x16_bf16(aQ1, bK1, accS, 0, 0, 0);
            f32x16 accT = __builtin_amdgcn_mfma_f32_32x32x16_bf16(bK0, aQ0, zacc, 0, 0, 0);
            accT        = __builtin_amdgcn_mfma_f32_32x32x16_bf16(bK1, aQ1, accT, 0, 0, 0);
#endif
            // accS: col=s, spans t -> max over t = score.max(axis=3)
            // accT: col=t, spans s -> max over s = score.max(axis=2)
            float m1 = halfmax(redmax16(accS));
            float m2 = halfmax(redmax16(accT));
            float v = m1 + m2;
            if (h == 0) vb[(kl << 5) + (t ^ kl)] = v;   // conflict-free swizzle
        }

        // ---- per-chunk epilogue (same-wave vbuf reuse, no barrier) ----
        {
            const int p    = lane & 7;
            const int half = (lane >> 3) & 1;
            float x[16];
#pragma unroll
            for (int i = 0; i < 16; ++i)
                x[i] = vb[(p << 5) + (((half << 4) + i) ^ p)];
            float s0 = (x[0] + x[1]) + (x[2] + x[3]);
            float s1 = (x[4] + x[5]) + (x[6] + x[7]);
            float s2 = (x[8] + x[9]) + (x[10] + x[11]);
            float s3 = (x[12] + x[13]) + (x[14] + x[15]);
            float sum = (s0 + s1) + (s2 + s3);
            sum += __shfl_xor(sum, 8);            // combine the two 16-halves
            float r = 1.0f / (1.0f + __expf(-sum * (1.0f / 64.0f)));
            if (lane < 8) {
                const int idx = q * KN + k0 + p;
                out[idx] = r;
                out[idx + QN * KN] = r;
            }
        }

        // ---- stage next chunk into the idle buffer ----
        if (c + 1 < NKC) {
            __syncthreads();            // all waves done with Kf[buf^1]'s last use
            __bf16* base = Kf[buf ^ 1] + skl * 768;
            if (hf == 0) {
                bf16x8 a;
                a[0] = (__bf16)pf0.x; a[1] = (__bf16)pf0.y; a[2] = (__bf16)pf0.z; a[3] = (__bf16)pf0.w;
                a[4] = (__bf16)pf1.x; a[5] = (__bf16)pf1.y; a[6] = (__bf16)pf1.z; a[7] = (__bf16)pf1.w;
                *(bf16x8*)(base + ss * 8) = a;
                bf16x4 b;
                b[0] = (__bf16)pf2.x; b[1] = (__bf16)pf2.y; b[2] = (__bf16)pf2.z; b[3] = (__bf16)pf2.w;
                *(bf16x4*)(base + (32 + ss) * 8) = b;
            } else {
                bf16x4 b;
                b[0] = (__bf16)pf0.x; b[1] = (__bf16)pf0.y; b[2] = (__bf16)pf0.z; b[3] = (__bf16)pf0.w;
                *(bf16x4*)(base + (32 + ss) * 8 + 4) = b;
                bf16x8 cdat;
                cdat[0] = (__bf16)pf1.x; cdat[1] = (__bf16)pf1.y; cdat[2] = (__bf16)pf1.z; cdat[3] = (__bf16)pf1.w;
                cdat[4] = (__bf16)pf2.x; cdat[5] = (__bf16)pf2.y; cdat[6] = (__bf16)pf2.z; cdat[7] = (__bf16)pf2.w;
                *(bf16x8*)(base + 512 + ss * 8) = cdat;
            }
            __syncthreads();            // next buffer ready
        }
    }
}

extern "C" void kernel_launch(void* const* d_in, const int* in_sizes, int n_in,
                              void* d_out, int out_size, void* d_ws, size_t ws_size,
                              hipStream_t stream)
{
    const float* tgt = (const float*)d_in[0];
    const float* mem = (const float*)d_in[1];
    float* out = (float*)d_out;
    dim3 grid(QN / WPB * KN / (KCH * NKC));   // 1024 blocks, 1D, XCD-swizzled
    matcher_kernel<<<grid, 512, 0, stream>>>(tgt, mem, out);
}